// Round 4
// baseline (484.865 us; speedup 1.0000x reference)
//
#include <hip/hip_runtime.h>
#include <hip/hip_bf16.h>
#include <hip/hip_fp16.h>

#define NN 4096

typedef __attribute__((ext_vector_type(8))) __bf16 bf16x8;
typedef __attribute__((ext_vector_type(4))) float f32x4;
typedef __attribute__((ext_vector_type(16))) float f32x16;
typedef __attribute__((ext_vector_type(8))) _Float16 f16x8;

static __device__ __forceinline__ unsigned short f2bf_bits(float x) {
  __hip_bfloat16 h = __float2bfloat16(x);
  return __builtin_bit_cast(unsigned short, h);
}

// ---------------------------------------------------------------------------
// Kernel 1: cast outer -> bf16, and compute s[row] = sum_j outer[row][j]
// ---------------------------------------------------------------------------
__global__ __launch_bounds__(256) void cast_rowsum_kernel(
    const float* __restrict__ in, __hip_bfloat16* __restrict__ ob,
    float* __restrict__ s) {
  const int row = blockIdx.x;
  const int t = threadIdx.x;
  const float4* rp = (const float4*)(in + (size_t)row * NN);
  unsigned short* op = (unsigned short*)(ob + (size_t)row * NN);
  float sum = 0.f;
#pragma unroll
  for (int it = 0; it < 4; ++it) {
    const int idx = it * 256 + t;
    float4 v = rp[idx];
    sum += (v.x + v.y) + (v.z + v.w);
    ushort4 b;
    b.x = f2bf_bits(v.x);
    b.y = f2bf_bits(v.y);
    b.z = f2bf_bits(v.z);
    b.w = f2bf_bits(v.w);
    *(ushort4*)(op + idx * 4) = b;
  }
#pragma unroll
  for (int o = 32; o > 0; o >>= 1) sum += __shfl_xor(sum, o);
  __shared__ float r[4];
  if ((t & 63) == 0) r[t >> 6] = sum;
  __syncthreads();
  if (t == 0) s[row] = (r[0] + r[1]) + (r[2] + r[3]);
}

// ---------------------------------------------------------------------------
// Kernel 2: plain cast f32 -> bf16
// ---------------------------------------------------------------------------
__global__ __launch_bounds__(256) void cast_kernel(
    const float* __restrict__ in, __hip_bfloat16* __restrict__ ob) {
  const size_t idx = ((size_t)blockIdx.x * 256 + threadIdx.x) * 4;
  float4 v = *(const float4*)(in + idx);
  ushort4 b;
  b.x = f2bf_bits(v.x);
  b.y = f2bf_bits(v.y);
  b.z = f2bf_bits(v.z);
  b.w = f2bf_bits(v.w);
  *(ushort4*)((unsigned short*)ob + idx) = b;
}

// ---------------------------------------------------------------------------
// GEMM: C[i,j] = sigmoid( sum_m A[i,m]*B[j,m] + bias[bias_row?i:j] )
// 256x256 tile, BK=64, 8 waves (2Mx4N), mfma_f32_32x32x16_bf16.
// 4 phases/K-tile, ONE barrier per phase, in-tile A-read-ahead (double-banked
// A regs), deep staging calendar with single counted vmcnt(6) per K-tile.
// T2 granule-xor swizzle (0 conflicts measured), T5 setprio, T1 XCD swizzle.
// ---------------------------------------------------------------------------
#define BAR() asm volatile("s_barrier" ::: "memory")
#define VMW(N) asm volatile("s_waitcnt vmcnt(" #N ")" ::: "memory")
#define MF32(a, b, c) __builtin_amdgcn_mfma_f32_32x32x16_bf16((a), (b), (c), 0, 0, 0)
#define NOOP ((void)0)

// staging: lane covers row (lane>>3), source granule (lane&7)^(row&7) so the
// LDS destination stays linear (global_load_lds) while reads xor the same way.
#define STAGE_A(dbuf, g, ktE)                                                  \
  do {                                                                         \
    const int r0_ = wm * 128 + (g) * 32 + (wid & 3) * 8;                       \
    __builtin_amdgcn_global_load_lds(                                          \
        (const __attribute__((address_space(1))) void*)(Ag +                   \
            ((size_t)r0_ << 12) + (ktE) + lrowoff),                            \
        (__attribute__((address_space(3))) void*)(&As[dbuf][r0_ * 64]), 16, 0, \
        0);                                                                    \
  } while (0)

#define STAGE_B(dbuf, q, ktE)                                                  \
  do {                                                                         \
    const int r0_ = (q) * 64 + wid * 8;                                        \
    __builtin_amdgcn_global_load_lds(                                          \
        (const __attribute__((address_space(1))) void*)(Bg +                   \
            ((size_t)r0_ << 12) + (ktE) + lrowoff),                            \
        (__attribute__((address_space(3))) void*)(&Bs[dbuf][r0_ * 64]), 16, 0, \
        0);                                                                    \
  } while (0)

#define NOSA(a, b, c) ((void)0)
#define NOSB(a, b, c) ((void)0)

#define LDA8(cb, off) (*(const bf16x8*)((const char*)As[cb] + (off)))
#define LDB8(cb, off) (*(const bf16x8*)((const char*)Bs[cb] + (off)))

// A-frags for m-slab g (rows g*32.., all 4 k-steps) into bank bk
#define LOAD_A32(cb, g, bk)                                                    \
  af[bk][0] = LDA8(cb, aBase + (g)*4096 + ak0);                                \
  af[bk][1] = LDA8(cb, aBase + (g)*4096 + ak1);                                \
  af[bk][2] = LDA8(cb, aBase + (g)*4096 + ak2);                                \
  af[bk][3] = LDA8(cb, aBase + (g)*4096 + ak3);

// all B-frags (2 n-frags x 4 k-steps), live across the whole K-tile
#define LOAD_B32(cb)                                                           \
  bfr[0][0] = LDB8(cb, bBase + ak0);                                           \
  bfr[0][1] = LDB8(cb, bBase + ak1);                                           \
  bfr[0][2] = LDB8(cb, bBase + ak2);                                           \
  bfr[0][3] = LDB8(cb, bBase + ak3);                                           \
  bfr[1][0] = LDB8(cb, bBase + 4096 + ak0);                                    \
  bfr[1][1] = LDB8(cb, bBase + 4096 + ak1);                                    \
  bfr[1][2] = LDB8(cb, bBase + 4096 + ak2);                                    \
  bfr[1][3] = LDB8(cb, bBase + 4096 + ak3);

// one m-slab x both n-frags x K=64: 8 MFMA, 2 interleaved dep-chains
#define MFMA_PH32(g, bk)                                                       \
  __builtin_amdgcn_s_setprio(1);                                               \
  acc[g][0] = MF32(af[bk][0], bfr[0][0], acc[g][0]);                           \
  acc[g][1] = MF32(af[bk][0], bfr[1][0], acc[g][1]);                           \
  acc[g][0] = MF32(af[bk][1], bfr[0][1], acc[g][0]);                           \
  acc[g][1] = MF32(af[bk][1], bfr[1][1], acc[g][1]);                           \
  acc[g][0] = MF32(af[bk][2], bfr[0][2], acc[g][0]);                           \
  acc[g][1] = MF32(af[bk][2], bfr[1][2], acc[g][1]);                           \
  acc[g][0] = MF32(af[bk][3], bfr[0][3], acc[g][0]);                           \
  acc[g][1] = MF32(af[bk][3], bfr[1][3], acc[g][1]);                           \
  __builtin_amdgcn_s_setprio(0);

// Tile X (buf cb), 4 phases, 1 barrier each.  Staging calendar (= R3, deep):
//   ph0: A q2,q3(X+1)->cb^1   ph1: B q0,q1(X+2)->cb   ph2: B q2,q3(X+2)->cb
//   ph3: A q0,q1(X+2)->cb ; VMW(6) retires all of X+1, keeps X+2's 6 in flight
// Reads: ph0: B(8) + A0(4) + A1-ahead(4); ph1: A2; ph2: A3; ph3: none.
#define KTILE32(cb, kn1, kn2, SA0, SBX, SA3, W)                                \
  {                                                                            \
    LOAD_B32(cb);                                                              \
    LOAD_A32(cb, 0, 0);                                                        \
    LOAD_A32(cb, 1, 1);                                                        \
    SA0((cb) ^ 1, 2, kn1);                                                     \
    SA0((cb) ^ 1, 3, kn1);                                                     \
    MFMA_PH32(0, 0);                                                           \
    BAR();                                                                     \
    LOAD_A32(cb, 2, 0);                                                        \
    SBX(cb, 0, kn2);                                                           \
    SBX(cb, 1, kn2);                                                           \
    MFMA_PH32(1, 1);                                                           \
    BAR();                                                                     \
    LOAD_A32(cb, 3, 1);                                                        \
    SBX(cb, 2, kn2);                                                           \
    SBX(cb, 3, kn2);                                                           \
    MFMA_PH32(2, 0);                                                           \
    BAR();                                                                     \
    SA3(cb, 0, kn2);                                                           \
    SA3(cb, 1, kn2);                                                           \
    MFMA_PH32(3, 1);                                                           \
    W;                                                                         \
    BAR();                                                                     \
  }

__global__ __launch_bounds__(512, 2) void gemm_sig(
    const unsigned short* __restrict__ Aq, const unsigned short* __restrict__ Bq,
    const unsigned short* __restrict__ Ak, const unsigned short* __restrict__ Bk,
    const float* __restrict__ bias_q, const float* __restrict__ bias_k,
    __half* __restrict__ Cq, __half* __restrict__ Ck) {
  __shared__ __align__(128) unsigned short As[2][16384];
  __shared__ __align__(128) unsigned short Bs[2][16384];

  const int tid = threadIdx.x;
  const int wid = tid >> 6;
  const int lane = tid & 63;
  const int wm = wid >> 2;  // 0..1
  const int wn = wid & 3;   // 0..3

  // dual-GEMM: blocks 0..255 = q-gemm, 256..511 = k-gemm
  const int sel = blockIdx.x >> 8;
  const unsigned short* __restrict__ A = sel ? Ak : Aq;
  const unsigned short* __restrict__ B = sel ? Bk : Bq;
  const float* __restrict__ bias = sel ? bias_k : bias_q;
  __half* __restrict__ C = sel ? Ck : Cq;
  const int bias_row = sel;

  // T1: bijective XCD swizzle within each gemm's 256 blocks (16x16 tile grid)
  const int bid = blockIdx.x & 255;
  const int xcd = bid & 7;
  const int idx = bid >> 3;
  const int brow = ((xcd >> 1) * 4 + (idx >> 3)) * 256;
  const int bcol = ((xcd & 1) * 8 + (idx & 7)) * 256;

  const unsigned short* Ag = A + (size_t)brow * NN;
  const unsigned short* Bg = B + (size_t)bcol * NN;

  // staging per-lane: row lane>>3, src granule (lane&7)^(row&7)
  const size_t lrowoff =
      (size_t)(lane >> 3) * NN + (((lane & 7) ^ (lane >> 3)) * 8);

  // 32x32x16 fragment geometry: row = lane&31, k = (lane>>5)*8 + j
  const int l31 = lane & 31;
  const int l7 = lane & 7;
  const int hi = lane >> 5;
  const int aBase = (wm * 128 + l31) * 128;
  const int bBase = (wn * 64 + l31) * 128;
  const int ak0 = ((0 + hi) ^ l7) << 4;
  const int ak1 = ((2 + hi) ^ l7) << 4;
  const int ak2 = ((4 + hi) ^ l7) << 4;
  const int ak3 = ((6 + hi) ^ l7) << 4;

  f32x16 acc[4][2];
#pragma unroll
  for (int m = 0; m < 4; ++m)
#pragma unroll
    for (int n = 0; n < 2; ++n)
#pragma unroll
      for (int j = 0; j < 16; ++j) acc[m][n][j] = 0.f;

  bf16x8 bfr[2][4], af[2][4];

  // ---- prologue: 14 issues, FIFO order matches the steady-state ledger ----
  STAGE_B(0, 0, 0);
  STAGE_B(0, 1, 0);
  STAGE_B(0, 2, 0);
  STAGE_B(0, 3, 0);
  STAGE_A(0, 0, 0);
  STAGE_A(0, 1, 0);
  STAGE_A(0, 2, 0);
  STAGE_A(0, 3, 0);
  STAGE_B(1, 0, 64);
  STAGE_B(1, 1, 64);
  STAGE_B(1, 2, 64);
  STAGE_B(1, 3, 64);
  STAGE_A(1, 0, 64);
  STAGE_A(1, 1, 64);
  VMW(6);  // retires tile0's 8 chunks; tile1's 6 stay in flight
  BAR();

  // ---- main loop: tiles 0..61 (uniform), 2 per iteration ----
  int kt = 0;
  for (int it = 0; it < 31; ++it) {
    KTILE32(0, kt + 64, kt + 128, STAGE_A, STAGE_B, STAGE_A, VMW(6));
    KTILE32(1, kt + 128, kt + 192, STAGE_A, STAGE_B, STAGE_A, VMW(6));
    kt += 128;
  }
  // ---- epilogue: tile 62 stages A q2,q3 of 63 then drains; tile 63 bare ----
  KTILE32(0, 4032, 0, STAGE_A, NOSB, NOSA, VMW(0));
  KTILE32(1, 0, 0, NOSA, NOSB, NOSA, NOOP);

  // ---- C write: 32x32 layout col=lane&31, row=(reg&3)+8*(reg>>2)+4*hi ----
#pragma unroll
  for (int mf = 0; mf < 4; ++mf) {
#pragma unroll
    for (int nf = 0; nf < 2; ++nf) {
#pragma unroll
      for (int j = 0; j < 16; ++j) {
        const int gi = brow + wm * 128 + mf * 32 + (j & 3) + 8 * (j >> 2) + 4 * hi;
        const int gj = bcol + wn * 64 + nf * 32 + l31;
        float v = acc[mf][nf][j] + (bias_row ? bias[gi] : bias[gj]);
        C[(size_t)gi * NN + gj] = __float2half(1.0f / (1.0f + __expf(-v)));
      }
    }
  }
}

// ---------------------------------------------------------------------------
// Kernel 5: out[i] = sum_j exp(q*k)*s[j] / sum_j exp(q*k); score in (0,1)
// ---------------------------------------------------------------------------
__global__ __launch_bounds__(256) void softmax_out_kernel(
    const __half* __restrict__ q, const __half* __restrict__ k,
    const float* __restrict__ s, float* __restrict__ out) {
  const int i = blockIdx.x;
  const int t = threadIdx.x;
  const __half* qr = q + (size_t)i * NN;
  const __half* kr = k + (size_t)i * NN;
  float se = 0.f, ses = 0.f;
#pragma unroll
  for (int it = 0; it < 2; ++it) {
    const int j0 = (it * 256 + t) * 8;
    f16x8 qv = *(const f16x8*)(qr + j0);
    f16x8 kv = *(const f16x8*)(kr + j0);
    float4 s0 = *(const float4*)(s + j0);
    float4 s1 = *(const float4*)(s + j0 + 4);
    float sj[8] = {s0.x, s0.y, s0.z, s0.w, s1.x, s1.y, s1.z, s1.w};
#pragma unroll
    for (int u = 0; u < 8; ++u) {
      float sc = (float)qv[u] * (float)kv[u];
      float e = __expf(sc);
      se += e;
      ses += e * sj[u];
    }
  }
#pragma unroll
  for (int o = 32; o > 0; o >>= 1) {
    se += __shfl_xor(se, o);
    ses += __shfl_xor(ses, o);
  }
  __shared__ float r1[4], r2[4];
  if ((t & 63) == 0) {
    r1[t >> 6] = se;
    r2[t >> 6] = ses;
  }
  __syncthreads();
  if (t == 0)
    out[i] = ((r2[0] + r2[1]) + (r2[2] + r2[3])) /
             ((r1[0] + r1[1]) + (r1[2] + r1[3]));
}

// ---------------------------------------------------------------------------
extern "C" void kernel_launch(void* const* d_in, const int* in_sizes, int n_in,
                              void* d_out, int out_size, void* d_ws,
                              size_t ws_size, hipStream_t stream) {
  const float* outer = (const float*)d_in[0];
  const float* W_slice = (const float*)d_in[1];
  const float* b_slice = (const float*)d_in[2];
  const float* W_q = (const float*)d_in[3];
  const float* b_q = (const float*)d_in[4];
  float* out = (float*)d_out;

  char* ws = (char*)d_ws;
  const size_t MSZ = (size_t)NN * NN * 2;  // 32 MiB per N^2 16-bit matrix
  __hip_bfloat16* outer_bf = (__hip_bfloat16*)(ws);
  __hip_bfloat16* wsl_bf = (__hip_bfloat16*)(ws + MSZ);
  __hip_bfloat16* wq_bf = (__hip_bfloat16*)(ws + 2 * MSZ);
  __half* qh = (__half*)(ws + 3 * MSZ);
  __half* kh = (__half*)(ws + 4 * MSZ);
  float* s = (float*)(ws + 5 * MSZ);  // 16 KiB

  cast_rowsum_kernel<<<NN, 256, 0, stream>>>(outer, outer_bf, s);
  cast_kernel<<<NN * NN / 1024, 256, 0, stream>>>(W_slice, wsl_bf);
  cast_kernel<<<NN * NN / 1024, 256, 0, stream>>>(W_q, wq_bf);

  // blocks 0..255: q = sigmoid(outer@W_q^T + b_q[j])
  // blocks 256..511: k = sigmoid(W_slice@outer^T + b_slice[i])
  gemm_sig<<<512, 512, 0, stream>>>(
      (const unsigned short*)outer_bf, (const unsigned short*)wq_bf,
      (const unsigned short*)wsl_bf, (const unsigned short*)outer_bf, b_q,
      b_slice, qh, kh);

  softmax_out_kernel<<<NN, 256, 0, stream>>>(qh, kh, s, out);
}